// Round 6
// baseline (566.632 us; speedup 1.0000x reference)
//
#include <hip/hip_runtime.h>
#include <math.h>

#define DIM   1024
#define NE    64
#define BM    64
#define BK    16
#define NT    64                 // 1024/16 k-tiles
#define A_BYTES 4096             // 64 tok x 4 float4-slots (linear)
#define B_BYTES 20480            // 320 col x 4 float4-slots (kq source-swizzled)
#define TILE_BYTES (A_BYTES + B_BYTES)   // 24576; x2 buffers = 48 KB

// global -> LDS direct copy, 16B/lane; LDS dest = wave-uniform base + lane*16.
__device__ __forceinline__ void gload16(const void* gptr, void* lptr) {
  __builtin_amdgcn_global_load_lds(
      (const __attribute__((address_space(1))) unsigned int*)(unsigned long long)gptr,
      (__attribute__((address_space(3))) unsigned int*)(unsigned int)(unsigned long long)lptr,
      16, 0, 0);
}

__global__ __launch_bounds__(256)
void ur_fused(const float* __restrict__ hs,    // [M,1024]
              const float* __restrict__ Wr,    // [64,1024]
              const float* __restrict__ br,    // [64]
              const float* __restrict__ Wu1,   // [256,1024]
              const float* __restrict__ bu1,   // [256]
              const float* __restrict__ Wu2,   // [256]
              const float* __restrict__ bu2,   // [1]
              float* __restrict__ out,         // w[4M] | idx[4M] | k[M]
              int M) {
  __shared__ __align__(16) char smem[2 * TILE_BYTES];   // 48 KB

  const int tid = threadIdx.x;
  const int m0 = blockIdx.x * BM;
  const int r = tid >> 5;        // 0..7  -> tokens 8r..8r+7
  const int c = tid & 31;        // 0..31 -> cols c+32n, n=0..9

  // ---- staging: issue l covers LDS slots 256l+tid (16B each), linear dest ----
  // A (1 issue): slot = 4*ta + kqs; ta = tid>>2, kqs = tid&3; global linear.
  // B (5 issues): slot = 4*col + kqs; col = 64l + (tid>>2); source k-chunk
  //   kq_g = kqs ^ ((col>>1)&3) = (tid&3) ^ ((tid>>3)&3)  (l-invariant, m173).
  const int t4 = tid >> 2, k4 = tid & 3;
  const int kqg = k4 ^ ((tid >> 3) & 3);
  const char* pA  = (const char*)(hs + (size_t)(m0 + t4) * DIM) + (k4 << 4);
  const char* pB0 = (const char*)(Wr + (size_t)t4 * DIM) + (kqg << 4);
  const char* pB1 = (const char*)(Wu1 + (size_t)t4 * DIM) + (kqg << 4);
  const unsigned wb = (unsigned)(tid & ~63) * 16u;   // wave-uniform lane-0 part

  float acc[8][10];
#pragma unroll
  for (int j = 0; j < 8; ++j)
#pragma unroll
    for (int n = 0; n < 10; ++n) acc[j][n] = 0.f;

  char* const buf0 = smem;
  char* const buf1 = smem + TILE_BYTES;
  const int csw = (c >> 1) & 3;    // B read swizzle key

  auto stage = [&](char* base) {
    gload16(pA, base + wb);                          // A slots 0..255
#pragma unroll
    for (int l = 0; l < 2; ++l)                      // B cols 0..63 (Wr), 64..127
      gload16((l ? pB1 : pB0), base + A_BYTES + l * 4096 + wb);
#pragma unroll
    for (int l = 2; l < 5; ++l)                      // B cols 128..319 (Wu1)
      gload16(pB1 + (l - 1) * 262144, base + A_BYTES + l * 4096 + wb);
    pA += 64; pB0 += 64; pB1 += 64;                  // advance BK*4 bytes
  };

  auto compute = [&](const char* base) {
    const char* Ab = base + r * 512;                 // 8 tokens x 64 B
    const char* Bb = base + A_BYTES + c * 64;
#pragma unroll
    for (int kq = 0; kq < 4; ++kq) {
      float4 av[8];
#pragma unroll
      for (int j = 0; j < 8; ++j)                    // 2-addr broadcast reads
        av[j] = *reinterpret_cast<const float4*>(Ab + j * 64 + (kq << 4));
      const int qb = (kq ^ csw) << 4;
#pragma unroll
      for (int n = 0; n < 10; ++n) {
        const float4 bv = *reinterpret_cast<const float4*>(Bb + n * 2048 + qb);
#pragma unroll
        for (int j = 0; j < 8; ++j) {
          acc[j][n] = fmaf(av[j].x, bv.x, acc[j][n]);
          acc[j][n] = fmaf(av[j].y, bv.y, acc[j][n]);
          acc[j][n] = fmaf(av[j].z, bv.z, acc[j][n]);
          acc[j][n] = fmaf(av[j].w, bv.w, acc[j][n]);
        }
      }
    }
  };

#define WAIT6 asm volatile("s_waitcnt vmcnt(6)" ::: "memory")
#define WAIT0 asm volatile("s_waitcnt vmcnt(0)" ::: "memory")
#define BAR   __builtin_amdgcn_s_barrier()

  // ---- pipelined main loop: counted vmcnt, loads span barriers ----
  stage(buf0);                       // tile 0
#pragma unroll 1
  for (int it = 0; it < NT / 2 - 1; ++it) {   // tiles 2it, 2it+1
    stage(buf1);  WAIT6; BAR; compute(buf0); BAR;
    stage(buf0);  WAIT6; BAR; compute(buf1); BAR;
  }
  stage(buf1);  WAIT6; BAR; compute(buf0); BAR;   // tile 62
  WAIT0; BAR;  compute(buf1);                     // tile 63
  __syncthreads();     // tile buffers dead; overlay epilogue arrays

  // ---- epilogue: bias, GELU, uncertainty dot (overlaid LDS) ----
  float* Lg = reinterpret_cast<float*>(smem);                 // [64][65]
  float* Xp = reinterpret_cast<float*>(smem + 16640);         // [32][65]
  float* Xs = reinterpret_cast<float*>(smem + 16640 + 8320);  // [64]

  float xp[8] = {0, 0, 0, 0, 0, 0, 0, 0};
#pragma unroll
  for (int n = 0; n < 10; ++n) {
    int col = c + 32 * n;
    if (n < 2) {                   // router cols 0..63
      float bias = br[col];
#pragma unroll
      for (int j = 0; j < 8; ++j) Lg[(8 * r + j) * 65 + col] = acc[j][n] + bias;
    } else {                       // u1 cols 64..319
      int qd = col - NE;
      float w2 = Wu2[qd];
      float b1 = bu1[qd];
#pragma unroll
      for (int j = 0; j < 8; ++j) {
        float h = acc[j][n] + b1;
        float g = 0.5f * h * (1.f + erff(h * 0.70710678118654752440f));
        xp[j] = fmaf(g, w2, xp[j]);
      }
    }
  }
#pragma unroll
  for (int j = 0; j < 8; ++j) Xp[c * 65 + 8 * r + j] = xp[j];
  __syncthreads();

  if (tid < BM) {
    float x = bu2[0];
#pragma unroll
    for (int cc = 0; cc < 32; ++cc) x += Xp[cc * 65 + tid];
    Xs[tid] = x;
  }
  __syncthreads();

  // ---- per-token top-4 + masked softmax: one wave per token ----
  const int wave = tid >> 6;
  const int lane = tid & 63;
  const size_t Moff_i = 4 * (size_t)M;
  const size_t Moff_k = 8 * (size_t)M;

  for (int t = wave; t < BM; t += 4) {
    float cur = Lg[t * 65 + lane];
    float topv[4];
    int topi[4];
#pragma unroll
    for (int s = 0; s < 4; ++s) {
      float mv = cur;
      int mi = lane;
#pragma unroll
      for (int off = 32; off >= 1; off >>= 1) {
        float ov = __shfl_xor(mv, off, 64);
        int oi = __shfl_xor(mi, off, 64);
        if (ov > mv || (ov == mv && oi < mi)) { mv = ov; mi = oi; }
      }
      topv[s] = mv;
      topi[s] = mi;
      if (lane == mi) cur = -INFINITY;   // stable: lowest index wins ties
    }
    if (lane == 0) {
      const int token = m0 + t;
      float x = Xs[t];
      float u = 1.f / (1.f + expf(-x));
      float kf = fmaf(3.f, u, 1.f);
      int kv = (int)rintf(kf);           // round-half-even == jnp.round
      kv = kv < 1 ? 1 : (kv > 4 ? 4 : kv);

      float w[4];
#pragma unroll
      for (int s = 0; s < 4; ++s) w[s] = (s < kv) ? topv[s] : 0.f;
      float mx = fmaxf(fmaxf(w[0], w[1]), fmaxf(w[2], w[3]));
      float e[4], sum = 0.f;
#pragma unroll
      for (int s = 0; s < 4; ++s) { e[s] = expf(w[s] - mx); sum += e[s]; }
      float inv = 1.f / sum;
#pragma unroll
      for (int s = 0; s < 4; ++s) {
        out[(size_t)token * 4 + s] = e[s] * inv;
        out[Moff_i + (size_t)token * 4 + s] = (s < kv) ? (float)topi[s] : -1.0f;
      }
      out[Moff_k + token] = (float)kv;
    }
  }
}

extern "C" void kernel_launch(void* const* d_in, const int* in_sizes, int n_in,
                              void* d_out, int out_size, void* d_ws, size_t ws_size,
                              hipStream_t stream) {
  (void)n_in; (void)d_ws; (void)ws_size; (void)out_size;
  const float* hs  = (const float*)d_in[0];
  const float* Wr  = (const float*)d_in[1];
  const float* br  = (const float*)d_in[2];
  const float* Wu1 = (const float*)d_in[3];
  const float* bu1 = (const float*)d_in[4];
  const float* Wu2 = (const float*)d_in[5];
  const float* bu2 = (const float*)d_in[6];
  float* out = (float*)d_out;

  const int M = in_sizes[0] / DIM;  // 32768
  dim3 grid(M / BM);                // 512 blocks, 2/CU resident (48 KB LDS)
  dim3 block(256);
  hipLaunchKernelGGL(ur_fused, grid, block, 0, stream,
                     hs, Wr, br, Wu1, bu1, Wu2, bu2, out, M);
}

// Round 7
// 366.594 us; speedup vs baseline: 1.5457x; 1.5457x over previous
//
#include <hip/hip_runtime.h>
#include <math.h>

#define DIM   1024
#define NE    64
#define BM    32
#define BK    32
#define NT    32                 // 1024/32 k-tiles
#define A_BYTES 4096             // 32 tok x 8 float4-slots (linear)
#define B_BYTES 40960            // 320 col x 8 float4-slots (kq source-swizzled)
#define TILE_BYTES (A_BYTES + B_BYTES)   // 45056 -> 3 blocks/CU

// global -> LDS direct copy, 16B/lane; LDS dest = wave-uniform base + lane*16.
__device__ __forceinline__ void gload16(const void* gptr, void* lptr) {
  __builtin_amdgcn_global_load_lds(
      (const __attribute__((address_space(1))) unsigned int*)(unsigned long long)gptr,
      (__attribute__((address_space(3))) unsigned int*)(unsigned int)(unsigned long long)lptr,
      16, 0, 0);
}

__global__ __launch_bounds__(256)
void ur_fused(const float* __restrict__ hs,    // [M,1024]
              const float* __restrict__ Wr,    // [64,1024]
              const float* __restrict__ br,    // [64]
              const float* __restrict__ Wu1,   // [256,1024]
              const float* __restrict__ bu1,   // [256]
              const float* __restrict__ Wu2,   // [256]
              const float* __restrict__ bu2,   // [1]
              float* __restrict__ out,         // w[4M] | idx[4M] | k[M]
              int M) {
  __shared__ __align__(16) char smem[TILE_BYTES];

  const int tid = threadIdx.x;
  const int m0 = blockIdx.x * BM;
  const int r = tid >> 5;        // 0..7  -> tokens 4r..4r+3
  const int c = tid & 31;        // 0..31 -> cols c+32n, n=0..9

  // ---- staging (slot = 256l + tid, 16B each, linear LDS dest) ----
  // A (1 issue): slot = 8*ta + kq; ta = tid>>3, kq = tid&7; global linear.
  // B (10 issues): col = 32l + (tid>>3), kqs = tid&7; global k-chunk
  //   kq_g = kqs ^ (col&7) = (tid&7) ^ ((tid>>3)&7)   (l-invariant, m173).
  const int t8 = tid >> 3, k8 = tid & 7;
  const int kqg = k8 ^ (t8 & 7);
  const char* pA  = (const char*)(hs + (size_t)(m0 + t8) * DIM) + (k8 << 4);
  const char* pB0 = (const char*)(Wr + (size_t)t8 * DIM) + (kqg << 4);
  const char* pB1 = (const char*)(Wu1 + (size_t)t8 * DIM) + (kqg << 4);
  const unsigned wb = (unsigned)(tid & ~63) * 16u;   // wave-uniform lane-0 part

  float acc[4][10];
#pragma unroll
  for (int j = 0; j < 4; ++j)
#pragma unroll
    for (int n = 0; n < 10; ++n) acc[j][n] = 0.f;

  const char* Ab = smem + r * 512;                   // token 4r, slot byte 128*tok
  const char* Bb = smem + A_BYTES + c * 128;
  const int csw = c & 7;                             // B read swizzle key

#pragma unroll 1
  for (int t = 0; t < NT; ++t) {
    __syncthreads();   // previous tile's readers done
    gload16(pA, smem + wb);                          // A slots 0..255
    pA += 128;
#pragma unroll
    for (int l = 0; l < 2; ++l)                      // B cols 0..63 (Wr)
      gload16(pB0 + l * 131072, smem + A_BYTES + l * 4096 + wb);
#pragma unroll
    for (int l = 2; l < 10; ++l)                     // B cols 64..319 (Wu1)
      gload16(pB1 + (l - 2) * 131072, smem + A_BYTES + l * 4096 + wb);
    pB0 += 128;
    pB1 += 128;
    __syncthreads();   // drains vmcnt(0): tile resident

#pragma unroll
    for (int kq = 0; kq < 8; ++kq) {
      float4 av[4];
#pragma unroll
      for (int j = 0; j < 4; ++j)   // 2-distinct-addr broadcast reads
        av[j] = *reinterpret_cast<const float4*>(Ab + j * 128 + (kq << 4));
      const int qb = (kq ^ csw) << 4;
#pragma unroll
      for (int n = 0; n < 10; ++n) {
        const float4 bv = *reinterpret_cast<const float4*>(Bb + n * 4096 + qb);
#pragma unroll
        for (int j = 0; j < 4; ++j) {
          acc[j][n] = fmaf(av[j].x, bv.x, acc[j][n]);
          acc[j][n] = fmaf(av[j].y, bv.y, acc[j][n]);
          acc[j][n] = fmaf(av[j].z, bv.z, acc[j][n]);
          acc[j][n] = fmaf(av[j].w, bv.w, acc[j][n]);
        }
      }
    }
  }
  __syncthreads();     // tile buffer dead; overlay epilogue arrays

  // ---- epilogue: bias, GELU, uncertainty dot (overlaid LDS) ----
  float* Lg = reinterpret_cast<float*>(smem);                // [32][65]
  float* Xp = reinterpret_cast<float*>(smem + 8320);         // [32][33]
  float* Xs = reinterpret_cast<float*>(smem + 8320 + 4224);  // [32]

  float xp[4] = {0.f, 0.f, 0.f, 0.f};
#pragma unroll
  for (int n = 0; n < 10; ++n) {
    int col = c + 32 * n;
    if (n < 2) {                   // router cols 0..63
      float bias = br[col];
#pragma unroll
      for (int j = 0; j < 4; ++j) Lg[(4 * r + j) * 65 + col] = acc[j][n] + bias;
    } else {                       // u1 cols 64..319
      int qd = col - NE;
      float w2 = Wu2[qd];
      float b1 = bu1[qd];
#pragma unroll
      for (int j = 0; j < 4; ++j) {
        float h = acc[j][n] + b1;
        float g = 0.5f * h * (1.f + erff(h * 0.70710678118654752440f));
        xp[j] = fmaf(g, w2, xp[j]);
      }
    }
  }
#pragma unroll
  for (int j = 0; j < 4; ++j) Xp[c * 33 + 4 * r + j] = xp[j];
  __syncthreads();

  if (tid < BM) {
    float x = bu2[0];
#pragma unroll
    for (int cc = 0; cc < 32; ++cc) x += Xp[cc * 33 + tid];
    Xs[tid] = x;
  }
  __syncthreads();

  // ---- per-token top-4 + masked softmax: one wave per token ----
  const int wave = tid >> 6;
  const int lane = tid & 63;
  const size_t Moff_i = 4 * (size_t)M;
  const size_t Moff_k = 8 * (size_t)M;

  for (int t = wave; t < BM; t += 4) {
    float cur = Lg[t * 65 + lane];
    float topv[4];
    int topi[4];
#pragma unroll
    for (int s = 0; s < 4; ++s) {
      float mv = cur;
      int mi = lane;
#pragma unroll
      for (int off = 32; off >= 1; off >>= 1) {
        float ov = __shfl_xor(mv, off, 64);
        int oi = __shfl_xor(mi, off, 64);
        if (ov > mv || (ov == mv && oi < mi)) { mv = ov; mi = oi; }
      }
      topv[s] = mv;
      topi[s] = mi;
      if (lane == mi) cur = -INFINITY;   // stable: lowest index wins ties
    }
    if (lane == 0) {
      const int token = m0 + t;
      float x = Xs[t];
      float u = 1.f / (1.f + expf(-x));
      float kf = fmaf(3.f, u, 1.f);
      int kv = (int)rintf(kf);           // round-half-even == jnp.round
      kv = kv < 1 ? 1 : (kv > 4 ? 4 : kv);

      float w[4];
#pragma unroll
      for (int s = 0; s < 4; ++s) w[s] = (s < kv) ? topv[s] : 0.f;
      float mx = fmaxf(fmaxf(w[0], w[1]), fmaxf(w[2], w[3]));
      float e[4], sum = 0.f;
#pragma unroll
      for (int s = 0; s < 4; ++s) { e[s] = expf(w[s] - mx); sum += e[s]; }
      float inv = 1.f / sum;
#pragma unroll
      for (int s = 0; s < 4; ++s) {
        out[(size_t)token * 4 + s] = e[s] * inv;
        out[Moff_i + (size_t)token * 4 + s] = (s < kv) ? (float)topi[s] : -1.0f;
      }
      out[Moff_k + token] = (float)kv;
    }
  }
}

extern "C" void kernel_launch(void* const* d_in, const int* in_sizes, int n_in,
                              void* d_out, int out_size, void* d_ws, size_t ws_size,
                              hipStream_t stream) {
  (void)n_in; (void)d_ws; (void)ws_size; (void)out_size;
  const float* hs  = (const float*)d_in[0];
  const float* Wr  = (const float*)d_in[1];
  const float* br  = (const float*)d_in[2];
  const float* Wu1 = (const float*)d_in[3];
  const float* bu1 = (const float*)d_in[4];
  const float* Wu2 = (const float*)d_in[5];
  const float* bu2 = (const float*)d_in[6];
  float* out = (float*)d_out;

  const int M = in_sizes[0] / DIM;  // 32768
  dim3 grid(M / BM);                // 1024 blocks, 3 resident/CU (44 KB LDS)
  dim3 block(256);
  hipLaunchKernelGGL(ur_fused, grid, block, 0, stream,
                     hs, Wr, br, Wu1, bu1, Wu2, bu2, out, M);
}